// Round 10
// baseline (207.324 us; speedup 1.0000x reference)
//
#include <hip/hip_runtime.h>

#define BD 8192
#define DD 512
#define KSPLIT 32
#define NELEM (DD * DD)          // 262144

typedef __attribute__((ext_vector_type(4))) float f32x4;
typedef __attribute__((ext_vector_type(8))) short short8;

__device__ __forceinline__ float polyev2(float c0, float c1, float c2, float w, float w2) {
    return c0 + c1 * w + c2 * w2;
}

// float -> bf16 bits, round-to-nearest-even (identical to verified prep path)
__device__ __forceinline__ unsigned short f2b(float v) {
    unsigned u = __builtin_bit_cast(unsigned, v);
    u += 0x7FFFu + ((u >> 16) & 1u);
    return (unsigned short)(u >> 16);
}

// ===========================================================================
// R10 structure: NO plane round-trip. gemm2 reads x,s,y fp32 directly,
// builds bf16 A/B panels in-register (A1/A2/A3 combos + x/x^2), stages via
// ds_write_b128 into a padded LDS image (80B/col: 32 bf16 + 8 pad shorts ->
// 2-way-max bank aliasing on both read and write, 16B aligned), and folds the
// 12 column-sums into the staging loops (duty split by (ks<16, tileI/tileO
// windows); csp written exactly once, no atomics).
// NOTE (R5/R7 lesson): phases communicate through kernel boundaries, NOT
//   grid.sync / in-kernel fan-in — cross-XCD reads of other-L2-dirty lines run
//   at ~530 GB/s; the kernel-boundary L2 flush is the cheap coherence path.
// NOTE (R9 lesson): 128x128 tiles beat 64x128 here — smaller tiles trade part
//   traffic for re-fetched panels at a net loss.
// ===========================================================================

// grid 512: ks = (bid&7)+((bid>>7)<<3) (same-ks blocks share bid%8 -> XCD class),
// tile=(bid>>3)&15 -> tileO (o/128), tileI (i/128).
// Merged phase st=0..15: rows (ks&15)*512 + st*32; A = ks<16 ? A1 : A2; B = ks<16 ? x : x^2.
// W phase st=16..23: rows ks*256 + (st-16)*32; A = A3; B = x.
// part[ks][o][i] = accM + w*accW.
__global__ __launch_bounds__(256, 2) void gemm2_kernel(
    const float* __restrict__ x, const float* __restrict__ s,
    const float* __restrict__ y, const float* __restrict__ w,
    const float* __restrict__ pw,
    float* __restrict__ part, float* __restrict__ csp)
{
    __shared__ short lds[2][2][128 * 40];   // [buf][A=0/B=1][col*40 + k] (80B stride)

    const int t    = threadIdx.x;
    const int lane = t & 63;
    const int wid  = t >> 6;
    const int bid  = blockIdx.x;
    const int ks   = (bid & 7) + ((bid >> 7) << 3);
    const int tile = (bid >> 3) & 15;
    const int tileI = tile & 3;
    const int tileO = tile >> 2;
    const int wo = (wid >> 1) * 64, wi = (wid & 1) * 64;
    const int l15 = lane & 15, g4 = lane >> 4;

    // staging identity: lane owns 2 cols (cp) x 8 rows (quarter q) per step
    const int q    = lane >> 4;             // 0..3
    const int cp   = (lane & 15) * 2;       // 0..30
    const int lcA  = wid * 32 + cp;         // local col 0..127
    const int colA = tileO * 128 + lcA;     // global A col (s,y)
    const int colB = tileI * 128 + lcA;     // global B col (x)

    const float p23 = pw[23], p24 = pw[24], p25 = pw[25], p26 = pw[26], p27 = pw[27];
    const float p28 = pw[28], p29 = pw[29], p32 = pw[32], p33 = pw[33];
    const bool half2 = (ks >= 16);

    f32x4 accM[4][4], accW[4][4];
#pragma unroll
    for (int m = 0; m < 4; ++m)
#pragma unroll
        for (int n = 0; n < 4; ++n) { accM[m][n] = (f32x4)0.f; accW[m][n] = (f32x4)0.f; }

    float smA[2][9];   // per col j: Ss,Ss2,Ss3,Sy,Sy2,Sy3,Ssy,Ss2y,Ssy2
    float smB[2][3];   // Sx,Sx2,Sx3
#pragma unroll
    for (int j = 0; j < 2; ++j) {
#pragma unroll
        for (int v = 0; v < 9; ++v) smA[j][v] = 0.f;
#pragma unroll
        for (int v = 0; v < 3; ++v) smB[j][v] = 0.f;
    }

    float2 rs[8], ry[8], rx[8];   // stage regs (48 floats)

    auto LOAD = [&](int R0) {
#pragma unroll
        for (int p = 0; p < 8; ++p) {
            const int r = R0 + q * 8 + p;
            rs[p] = *(const float2*)&s[(size_t)r * DD + colA];
            ry[p] = *(const float2*)&y[(size_t)r * DD + colA];
            rx[p] = *(const float2*)&x[(size_t)r * DD + colB];
        }
    };

    // mode: 0=A1, 1=A2, 2=A3; bx2: B is x^2
    auto WRITE = [&](int buf, int mode, bool bx2, bool sumA, bool sumB) {
        unsigned pa[2][4], pb[2][4];
#pragma unroll
        for (int p = 0; p < 8; ++p) {
            const float sv[2] = { rs[p].x, rs[p].y };
            const float yv[2] = { ry[p].x, ry[p].y };
            const float xv[2] = { rx[p].x, rx[p].y };
#pragma unroll
            for (int j = 0; j < 2; ++j) {
                const float S = sv[j], Y = yv[j], X = xv[j];
                const float S2 = S * S, Y2 = Y * Y;
                float av;
                if (mode == 0)      av = p26 * S + p23 * Y + p29 * S2 + p25 * Y2 + p28 * (S * Y);
                else if (mode == 1) av = p33 * S + p32 * Y;
                else                av = p27 * S + p24 * Y;
                const float X2 = X * X;
                const float bv = bx2 ? X2 : X;
                const unsigned short ab = f2b(av), bb = f2b(bv);
                if ((p & 1) == 0) { pa[j][p >> 1] = (unsigned)ab; pb[j][p >> 1] = (unsigned)bb; }
                else              { pa[j][p >> 1] |= (unsigned)ab << 16; pb[j][p >> 1] |= (unsigned)bb << 16; }
                if (sumA) {
                    smA[j][0] += S;     smA[j][1] += S2;     smA[j][2] += S2 * S;
                    smA[j][3] += Y;     smA[j][4] += Y2;     smA[j][5] += Y2 * Y;
                    smA[j][6] += S * Y; smA[j][7] += S2 * Y; smA[j][8] += S * Y2;
                }
                if (sumB) { smB[j][0] += X; smB[j][1] += X2; smB[j][2] += X2 * X; }
            }
        }
#pragma unroll
        for (int j = 0; j < 2; ++j) {
            uint4 ua; ua.x = pa[j][0]; ua.y = pa[j][1]; ua.z = pa[j][2]; ua.w = pa[j][3];
            uint4 ub; ub.x = pb[j][0]; ub.y = pb[j][1]; ub.z = pb[j][2]; ub.w = pb[j][3];
            *(uint4*)&lds[buf][0][(lcA + j) * 40 + q * 8] = ua;
            *(uint4*)&lds[buf][1][(lcA + j) * 40 + q * 8] = ub;
        }
    };

    auto MFMA = [&](int buf, f32x4 (&acc)[4][4]) {
        short8 af[4], bf[4];
#pragma unroll
        for (int m = 0; m < 4; ++m)
            af[m] = *(const short8*)&lds[buf][0][(wo + m * 16 + l15) * 40 + g4 * 8];
#pragma unroll
        for (int n = 0; n < 4; ++n)
            bf[n] = *(const short8*)&lds[buf][1][(wi + n * 16 + l15) * 40 + g4 * 8];
#pragma unroll
        for (int m = 0; m < 4; ++m)
#pragma unroll
            for (int n = 0; n < 4; ++n)
                acc[m][n] = __builtin_amdgcn_mfma_f32_16x16x32_bf16(af[m], bf[n], acc[m][n], 0, 0, 0);
    };

    const int Rm = (ks & 15) * 512;
    const int modeM = half2 ? 1 : 0;

    LOAD(Rm);
#pragma unroll 1
    for (int st = 0; st < 24; ++st) {
        const int buf = st & 1;
        const bool merged = st < 16;
        const bool sumA = !half2 && merged && ((st >> 2) == tileI);
        const bool sumB = !half2 && merged && ((st >> 2) == tileO);
        WRITE(buf, merged ? modeM : 2, merged && half2, sumA, sumB);
        if (st < 23) {
            const int nst = st + 1;
            const int R0n = (nst < 16) ? (Rm + nst * 32) : (ks * 256 + (nst - 16) * 32);
            LOAD(R0n);
        }
        __syncthreads();
        MFMA(buf, merged ? accM : accW);
        // single barrier per step is safe: writes at st+1 target buf^1, whose
        // last readers (MFMA at st-1) are separated by this step's barrier.
    }

    float* pout = part + (size_t)ks * NELEM;
#pragma unroll
    for (int m = 0; m < 4; ++m) {
        const int o = tileO * 128 + wo + m * 16 + g4 * 4;
#pragma unroll
        for (int n = 0; n < 4; ++n) {
            const int i = tileI * 128 + wi + n * 16 + l15;
#pragma unroll
            for (int r = 0; r < 4; ++r) {
                const float wv = w[(size_t)(o + r) * DD + i];
                pout[(size_t)(o + r) * DD + i] = accM[m][n][r] + wv * accW[m][n][r];
            }
        }
    }

    // column-sum partials: quarters combine via shfl (lanes l, l^16, l^32, l^48
    // share (wid,cp)); lanes<16 write. Exactly-once coverage:
    //   A: slot=ks*4+tileI covers rows ks*512+tileI*128..+128, cols per tileO.
    //   B: slot=ks*4+tileO, cols per tileI.
    if (!half2) {
#pragma unroll
        for (int j = 0; j < 2; ++j) {
#pragma unroll
            for (int v = 0; v < 9; ++v) {
                smA[j][v] += __shfl_xor(smA[j][v], 16, 64);
                smA[j][v] += __shfl_xor(smA[j][v], 32, 64);
            }
#pragma unroll
            for (int v = 0; v < 3; ++v) {
                smB[j][v] += __shfl_xor(smB[j][v], 16, 64);
                smB[j][v] += __shfl_xor(smB[j][v], 32, 64);
            }
        }
        if (lane < 16) {
            const int slotA = ks * 4 + tileI;
            const int slotB = ks * 4 + tileO;
#pragma unroll
            for (int j = 0; j < 2; ++j) {
#pragma unroll
                for (int v = 0; v < 9; ++v)
                    csp[((size_t)slotA * 12 + 3 + v) * DD + colA + j] = smA[j][v];
#pragma unroll
                for (int v = 0; v < 3; ++v)
                    csp[((size_t)slotB * 12 + v) * DD + colB + j] = smB[j][v];
            }
        }
    }
}

// cs[v][c] = sum over 64 slot-partials (1.5 MB read, tiny)
__global__ __launch_bounds__(256) void reduce_cs_kernel(
    const float* __restrict__ csp, float* __restrict__ cs)
{
    const int u = blockIdx.x * 256 + threadIdx.x;
    if (u < 12 * DD) {
        const int v = u >> 9;
        const int c = u & 511;
        float acc = 0.f;
#pragma unroll 4
        for (int slot = 0; slot < 64; ++slot)
            acc += csp[((size_t)slot * 12 + v) * DD + c];
        cs[v * DD + c] = acc;
    }
}

// ------------------------- epilogue (verified R6+) -------------------------
__device__ __forceinline__ void deltab_store(
    const int o, const float* __restrict__ bvec, const float* __restrict__ pb,
    const float* __restrict__ cs, float* __restrict__ out)
{
    const float bv = bvec[o];
    const float b2 = bv * bv, b3 = b2 * bv;
    const float invB = 1.0f / (float)BD;
    float acc = (float)BD * (pb[0] + pb[1] * bv + pb[2] * b2 + pb[3] * b3);
    acc += cs[6 * DD + o] * (pb[4] + pb[5] * bv + pb[6] * b2);
    acc += cs[7 * DD + o] * (pb[7] + pb[8] * bv);
    acc += cs[8 * DD + o] * pb[9];
    out[DD * DD + o] = invB * acc;
}

// grid 256 x 256 threads, 4 consecutive elements per thread (float4 I/O).
__global__ __launch_bounds__(256) void reduce_rank1_kernel(
    const float* __restrict__ part, const float* __restrict__ w,
    const float* __restrict__ pw, const float* __restrict__ cs,
    const float* __restrict__ bvec, const float* __restrict__ pb,
    float* __restrict__ out)
{
    const int t   = threadIdx.x;
    const int bid = blockIdx.x;
    const int idx = (bid * 256 + t) * 4;
    const int o   = idx >> 9;
    const int i0  = idx & 511;

    float4 g = {0.f, 0.f, 0.f, 0.f};
#pragma unroll
    for (int ks = 0; ks < KSPLIT; ++ks) {
        const float4 p = *(const float4*)&part[(size_t)ks * NELEM + idx];
        g.x += p.x; g.y += p.y; g.z += p.z; g.w += p.w;
    }
    const float4 wv4 = *(const float4*)&w[idx];

    const float csY1 = cs[6 * DD + o], csY2 = cs[7 * DD + o], csY3 = cs[8 * DD + o];
    const float csS1 = cs[3 * DD + o], csS2 = cs[4 * DD + o], csS3 = cs[5 * DD + o];
    const float csSY = cs[9 * DD + o], csS2Y = cs[10 * DD + o], csSY2 = cs[11 * DD + o];
    const float4 csX1 = *(const float4*)&cs[0 * DD + i0];
    const float4 csX2 = *(const float4*)&cs[1 * DD + i0];
    const float4 csX3 = *(const float4*)&cs[2 * DD + i0];

    const float ga[4]  = {g.x, g.y, g.z, g.w};
    const float wa[4]  = {wv4.x, wv4.y, wv4.z, wv4.w};
    const float cx1[4] = {csX1.x, csX1.y, csX1.z, csX1.w};
    const float cx2[4] = {csX2.x, csX2.y, csX2.z, csX2.w};
    const float cx3[4] = {csX3.x, csX3.y, csX3.z, csX3.w};

    float4 res;
    float ra[4];
#pragma unroll
    for (int l = 0; l < 4; ++l) {
        const float wv = wa[l];
        const float w2 = wv * wv, w3 = w2 * wv;
        float acc = (float)BD * (pw[0] + pw[1] * wv + pw[2] * w2 + pw[3] * w3);
        acc += cx1[l] * polyev2(pw[20], pw[21], pw[22], wv, w2);
        acc += cx2[l] * (pw[30] + pw[31] * wv);
        acc += cx3[l] * pw[34];
        acc += csY1 * polyev2(pw[4],  pw[5],  pw[6],  wv, w2);
        acc += csY2 * (pw[7] + pw[8] * wv);
        acc += csY3 * pw[9];
        acc += csS1 * polyev2(pw[10], pw[11], pw[12], wv, w2);
        acc += csSY * (pw[13] + pw[14] * wv);
        acc += csSY2 * pw[15];
        acc += csS2 * (pw[16] + pw[17] * wv);
        acc += csS2Y * pw[18];
        acc += csS3 * pw[19];
        ra[l] = (1.0f / (float)BD) * (ga[l] + acc);
    }
    res.x = ra[0]; res.y = ra[1]; res.z = ra[2]; res.w = ra[3];
    *(float4*)&out[idx] = res;

    if (bid == 0) {
        deltab_store(t,       bvec, pb, cs, out);
        deltab_store(t + 256, bvec, pb, cs, out);
    }
}

extern "C" void kernel_launch(void* const* d_in, const int* in_sizes, int n_in,
                              void* d_out, int out_size, void* d_ws, size_t ws_size,
                              hipStream_t stream) {
    const float* x  = (const float*)d_in[0];
    const float* s  = (const float*)d_in[1];
    const float* y  = (const float*)d_in[2];
    const float* w  = (const float*)d_in[3];
    const float* b  = (const float*)d_in[4];
    const float* pw = (const float*)d_in[5];
    const float* pb = (const float*)d_in[6];
    float* out = (float*)d_out;

    const size_t partBytes = (size_t)KSPLIT * NELEM * sizeof(float);  // 33.6 MB
    const size_t cspBytes  = (size_t)64 * 12 * DD * sizeof(float);    //  1.5 MB
    const size_t csBytes   = 12 * DD * sizeof(float);
    if (ws_size < partBytes + cspBytes + csBytes) return;

    float* part = (float*)d_ws;
    float* csp  = (float*)((char*)d_ws + partBytes);
    float* cs   = (float*)((char*)d_ws + partBytes + cspBytes);

    gemm2_kernel<<<512, 256, 0, stream>>>(x, s, y, w, pw, part, csp);
    reduce_cs_kernel<<<24, 256, 0, stream>>>(csp, cs);
    reduce_rank1_kernel<<<256, 256, 0, stream>>>(part, w, pw, cs, b, pb, out);
}